// Round 5
// baseline (1493.446 us; speedup 1.0000x reference)
//
#include <hip/hip_runtime.h>
#include <hip/hip_fp16.h>

#define BT 512            // threads per block (8 waves)
#define MSTEPS 8
#define NBMAX 512

struct PParams {
  const float* candidate;
  const float* z_past;
  const ushort* zh;       // fp16-converted z_past (F16 path)
  const float* q_w; const float* q_b;
  const float* k_w; const float* k_b;
  const float* v_w; const float* v_b;
  const float* o_w; const float* o_b;
  const float* rel_bias;
  const float* coupling;
  const float* norm_scale;
  float* out;
  float* part;   // 2 * 132 * NB floats (double-buffered partials)
  float* bcast;  // 384 floats: [0,128) = A table, [128,384) = Rel table
  int*   syn;    // 16 ints: [0,8) ready flags, [8,16) arrive counters
  int L;
  int NB;        // actual grid size
  int NQ;        // NB * (BT/4) quads
};

__device__ __forceinline__ float mish_f(float x) {
  float sp = fmaxf(x, 0.0f) + log1pf(expf(-fabsf(x)));
  return x * tanhf(sp);
}

// zero the sync words every launch (graph-replay safe)
__global__ void init_kernel(int* syn) {
  if (threadIdx.x < 16) syn[threadIdx.x] = 0;
}

// fp32 -> fp16 conversion pre-pass: one thread per 8 elements
__global__ void cvt_kernel(const float* __restrict__ z, ushort* __restrict__ zh, int n8) {
  int t = blockIdx.x * blockDim.x + threadIdx.x;
  if (t >= n8) return;
  const float4* s = reinterpret_cast<const float4*>(z) + 2 * (size_t)t;
  float4 a = s[0], b = s[1];
  __half2 h0 = __floats2half2_rn(a.x, a.y);
  __half2 h1 = __floats2half2_rn(a.z, a.w);
  __half2 h2 = __floats2half2_rn(b.x, b.y);
  __half2 h3 = __floats2half2_rn(b.z, b.w);
  uint4 o;
  o.x = *reinterpret_cast<unsigned*>(&h0);
  o.y = *reinterpret_cast<unsigned*>(&h1);
  o.z = *reinterpret_cast<unsigned*>(&h2);
  o.w = *reinterpret_cast<unsigned*>(&h3);
  reinterpret_cast<uint4*>(zh)[t] = o;
}

__device__ __forceinline__ void cvt8(const uint4& r, float zv[8]) {
  const __half2* h = reinterpret_cast<const __half2*>(&r);
  float2 f0 = __half22float2(h[0]);
  float2 f1 = __half22float2(h[1]);
  float2 f2 = __half22float2(h[2]);
  float2 f3 = __half22float2(h[3]);
  zv[0] = f0.x; zv[1] = f0.y; zv[2] = f1.x; zv[3] = f1.y;
  zv[4] = f2.x; zv[5] = f2.y; zv[6] = f3.x; zv[7] = f3.y;
}

template <bool REL>
__device__ __forceinline__ void accum_pos(const float A[4][8], const float zv[8],
                                          float S[4][8], float Zc[4],
                                          const float* sRel, int l) {
  float d[4] = {0.f, 0.f, 0.f, 0.f};
  #pragma unroll
  for (int h = 0; h < 4; ++h)
    #pragma unroll
    for (int k = 0; k < 8; ++k) d[h] = fmaf(A[h][k], zv[k], d[h]);
  #pragma unroll
  for (int h = 0; h < 4; ++h) {
    d[h] += __shfl_xor(d[h], 1);
    d[h] += __shfl_xor(d[h], 2);
  }
  if (REL) {
    if (l < 64) {
      const float4 r = reinterpret_cast<const float4*>(sRel)[l];
      d[0] += r.x; d[1] += r.y; d[2] += r.z; d[3] += r.w;
    }
  }
  #pragma unroll
  for (int h = 0; h < 4; ++h) {
    float w = __expf(d[h]);
    Zc[h] += w;
    #pragma unroll
    for (int k = 0; k < 8; ++k) S[h][k] = fmaf(w, zv[k], S[h][k]);
  }
}

// Recompute q projection, folded score vectors a_h (pre-scaled by inv_sqrt_d=0.5),
// and the l<64 relative-bias delta table, from the current state sZ.
// Block-level: contains barriers; called by all threads of the calling block.
__device__ void compute_qar(const PParams& p, int tid,
                            float* sZ, float* sQ, float* sA, float* sRel) {
  if (tid < 32) {
    float acc = p.q_b[tid];
    const float* row = p.q_w + tid * 32;
    #pragma unroll
    for (int c = 0; c < 32; ++c) acc = fmaf(row[c], sZ[c], acc);
    sQ[tid] = acc;
  }
  __syncthreads();
  if (tid < 128) {
    int h = tid >> 5, c = tid & 31;
    float acc = 0.f;
    #pragma unroll
    for (int jj = 0; jj < 8; ++jj)
      acc = fmaf(sQ[8 * h + jj], p.k_w[(8 * h + jj) * 32 + c], acc);
    sA[tid] = 0.5f * acc;               // fold inv_sqrt_d
  }
  if (tid >= 256 && tid < 512) {
    // rel-bias delta vs the saturated idx=128 entry (constant part cancels in softmax)
    int t = tid - 256;
    int l = t >> 2, h = t & 3;
    float acc = 0.f;
    #pragma unroll
    for (int jj = 0; jj < 8; ++jj) {
      int jidx = 8 * h + jj;
      acc = fmaf(sQ[jidx],
                 p.rel_bias[(l + 64) * 32 + jidx] - p.rel_bias[128 * 32 + jidx],
                 acc);
    }
    sRel[t] = 0.5f * acc;
  }
  __syncthreads();
}

template <bool F16>
__global__ __launch_bounds__(BT)
void photonic_kernel(PParams p) {
  __shared__ __align__(16) float sZ[32];
  __shared__ float sQ[32];
  __shared__ float sOutV[32];
  __shared__ float sZn[32];
  __shared__ __align__(16) float sA[128];     // a[h][c]
  __shared__ __align__(16) float sRel[256];   // relT[l][h], l<64
  __shared__ float sRed[BT / 64][4][36];      // per-wave reduced (S[4][8] + Z[4]) per quarter
  __shared__ float sSS[128];                  // global-reduced S[h][c]
  __shared__ float sSZ[4];                    // global-reduced Z[h]

  const int tid  = threadIdx.x;
  const int b    = blockIdx.x;
  const int j    = tid & 3;        // quarter (owns columns [8j, 8j+8))
  const int quad = tid >> 2;
  const int gq   = b * (BT / 4) + quad;
  const int wave = tid >> 6;
  const int lane = tid & 63;
  const int NQ   = p.NQ;
  const int NB   = p.NB;

  if (tid < 32) sZ[tid] = p.candidate[tid];
  __syncthreads();
  compute_qar(p, tid, sZ, sQ, sA, sRel);

  for (int iter = 0; iter < MSTEPS; ++iter) {
    float A[4][8];
    #pragma unroll
    for (int h = 0; h < 4; ++h)
      #pragma unroll
      for (int k = 0; k < 8; ++k)
        A[h][k] = sA[h * 32 + j * 8 + k];

    float S[4][8];
    #pragma unroll
    for (int h = 0; h < 4; ++h)
      #pragma unroll
      for (int k = 0; k < 8; ++k) S[h][k] = 0.f;
    float Zc[4] = {0.f, 0.f, 0.f, 0.f};

    int l = gq;
    if (F16) {
      const uint4* zp = reinterpret_cast<const uint4*>(p.zh);
      if (l + 3 * NQ < p.L) {
        uint4 r0 = zp[(size_t)l * 4 + j];
        uint4 r1 = zp[(size_t)(l + NQ) * 4 + j];
        uint4 r2 = zp[(size_t)(l + 2 * NQ) * 4 + j];
        uint4 r3 = zp[(size_t)(l + 3 * NQ) * 4 + j];
        float zv[8];
        cvt8(r0, zv); accum_pos<true >(A, zv, S, Zc, sRel, l);
        cvt8(r1, zv); accum_pos<false>(A, zv, S, Zc, sRel, l + NQ);
        cvt8(r2, zv); accum_pos<false>(A, zv, S, Zc, sRel, l + 2 * NQ);
        cvt8(r3, zv); accum_pos<false>(A, zv, S, Zc, sRel, l + 3 * NQ);
        l += 4 * NQ;
      }
      for (; l + 3 * NQ < p.L; l += 4 * NQ) {
        uint4 r0 = zp[(size_t)l * 4 + j];
        uint4 r1 = zp[(size_t)(l + NQ) * 4 + j];
        uint4 r2 = zp[(size_t)(l + 2 * NQ) * 4 + j];
        uint4 r3 = zp[(size_t)(l + 3 * NQ) * 4 + j];
        float zv[8];
        cvt8(r0, zv); accum_pos<false>(A, zv, S, Zc, sRel, l);
        cvt8(r1, zv); accum_pos<false>(A, zv, S, Zc, sRel, l + NQ);
        cvt8(r2, zv); accum_pos<false>(A, zv, S, Zc, sRel, l + 2 * NQ);
        cvt8(r3, zv); accum_pos<false>(A, zv, S, Zc, sRel, l + 3 * NQ);
      }
      for (; l < p.L; l += NQ) {
        uint4 r0 = zp[(size_t)l * 4 + j];
        float zv[8];
        cvt8(r0, zv); accum_pos<true>(A, zv, S, Zc, sRel, l);
      }
    } else {
      const float4* zp = reinterpret_cast<const float4*>(p.z_past);
      if (l + NQ < p.L) {
        float4 a0 = zp[(size_t)l * 8 + j * 2], b0 = zp[(size_t)l * 8 + j * 2 + 1];
        float4 a1 = zp[(size_t)(l + NQ) * 8 + j * 2], b1 = zp[(size_t)(l + NQ) * 8 + j * 2 + 1];
        float zv[8];
        zv[0]=a0.x; zv[1]=a0.y; zv[2]=a0.z; zv[3]=a0.w; zv[4]=b0.x; zv[5]=b0.y; zv[6]=b0.z; zv[7]=b0.w;
        accum_pos<true >(A, zv, S, Zc, sRel, l);
        zv[0]=a1.x; zv[1]=a1.y; zv[2]=a1.z; zv[3]=a1.w; zv[4]=b1.x; zv[5]=b1.y; zv[6]=b1.z; zv[7]=b1.w;
        accum_pos<false>(A, zv, S, Zc, sRel, l + NQ);
        l += 2 * NQ;
      }
      for (; l + NQ < p.L; l += 2 * NQ) {
        float4 a0 = zp[(size_t)l * 8 + j * 2], b0 = zp[(size_t)l * 8 + j * 2 + 1];
        float4 a1 = zp[(size_t)(l + NQ) * 8 + j * 2], b1 = zp[(size_t)(l + NQ) * 8 + j * 2 + 1];
        float zv[8];
        zv[0]=a0.x; zv[1]=a0.y; zv[2]=a0.z; zv[3]=a0.w; zv[4]=b0.x; zv[5]=b0.y; zv[6]=b0.z; zv[7]=b0.w;
        accum_pos<false>(A, zv, S, Zc, sRel, l);
        zv[0]=a1.x; zv[1]=a1.y; zv[2]=a1.z; zv[3]=a1.w; zv[4]=b1.x; zv[5]=b1.y; zv[6]=b1.z; zv[7]=b1.w;
        accum_pos<false>(A, zv, S, Zc, sRel, l + NQ);
      }
      for (; l < p.L; l += NQ) {
        float4 a0 = zp[(size_t)l * 8 + j * 2], b0 = zp[(size_t)l * 8 + j * 2 + 1];
        float zv[8];
        zv[0]=a0.x; zv[1]=a0.y; zv[2]=a0.z; zv[3]=a0.w; zv[4]=b0.x; zv[5]=b0.y; zv[6]=b0.z; zv[7]=b0.w;
        accum_pos<true>(A, zv, S, Zc, sRel, l);
      }
    }

    // reduce across the 16 quads of each wave (lane%4 == quarter is preserved)
    #pragma unroll
    for (int m = 4; m <= 32; m <<= 1) {
      #pragma unroll
      for (int h = 0; h < 4; ++h) {
        #pragma unroll
        for (int k = 0; k < 8; ++k) S[h][k] += __shfl_xor(S[h][k], m);
        Zc[h] += __shfl_xor(Zc[h], m);
      }
    }
    if ((lane >> 2) == 0) {  // lanes 0..3: lane == quarter j
      #pragma unroll
      for (int h = 0; h < 4; ++h) {
        #pragma unroll
        for (int k = 0; k < 8; ++k) sRed[wave][lane][h * 8 + k] = S[h][k];
        sRed[wave][lane][32 + h] = Zc[h];
      }
    }
    __syncthreads();

    // per-block partials -> global, component-major [comp][NB] for coalesced reduce
    float* part = p.part + (iter & 1) * (132 * NB);
    if (tid < 132) {
      float acc = 0.f;
      if (tid < 128) {
        int h = tid >> 5, c = tid & 31;
        int jj = c >> 3, k = c & 7;
        #pragma unroll
        for (int w2 = 0; w2 < BT / 64; ++w2) acc += sRed[w2][jj][h * 8 + k];
        part[(h * 33 + c) * NB + b] = acc;
      } else {
        int h = tid - 128;
        #pragma unroll
        for (int w2 = 0; w2 < BT / 64; ++w2) acc += sRed[w2][0][32 + h];
        part[(h * 33 + 32) * NB + b] = acc;
      }
    }
    __threadfence();
    __syncthreads();
    if (tid == 0)
      __hip_atomic_fetch_add(&p.syn[8 + iter], 1, __ATOMIC_RELEASE, __HIP_MEMORY_SCOPE_AGENT);

    if (b == 0) {
      // ---- single-owner reduce + state update ----
      if (tid == 0) {
        while (__hip_atomic_load(&p.syn[8 + iter], __ATOMIC_ACQUIRE, __HIP_MEMORY_SCOPE_AGENT) < NB)
          __builtin_amdgcn_s_sleep(2);
      }
      __syncthreads();
      {
        // S components: 4 threads per component (512 threads for 128 comps)
        int comp = tid >> 2, seg = tid & 3;       // comp in [0,128)
        int h = comp >> 5, c = comp & 31;
        const float4* pp = reinterpret_cast<const float4*>(part + (h * 33 + c) * NB + seg * (NB / 4));
        float acc = 0.f;
        const int nit = NB / 16;
        for (int i = 0; i < nit; ++i) {
          float4 v4 = pp[i];
          acc += (v4.x + v4.y) + (v4.z + v4.w);
        }
        acc += __shfl_xor(acc, 1);
        acc += __shfl_xor(acc, 2);
        if (seg == 0) sSS[comp] = acc;
      }
      if (tid < 16) {
        // Z components: 4 threads per head
        int h = tid >> 2, seg = tid & 3;
        const float4* pp = reinterpret_cast<const float4*>(part + (h * 33 + 32) * NB + seg * (NB / 4));
        float acc = 0.f;
        const int nit = NB / 16;
        for (int i = 0; i < nit; ++i) {
          float4 v4 = pp[i];
          acc += (v4.x + v4.y) + (v4.z + v4.w);
        }
        acc += __shfl_xor(acc, 1);
        acc += __shfl_xor(acc, 2);
        if (seg == 0) sSZ[h] = acc;
      }
      __syncthreads();

      // out_flat[j'] = v_w[j',:] @ (S_h / Z_h) + v_b[j']   (h = j'>>3)
      if (tid < 32) {
        int h = tid >> 3;
        float acc = 0.f;
        const float* row = p.v_w + tid * 32;
        #pragma unroll
        for (int c = 0; c < 32; ++c) acc = fmaf(row[c], sSS[h * 32 + c], acc);
        sOutV[tid] = acc / sSZ[h] + p.v_b[tid];
      }
      __syncthreads();
      if (tid < 32) {
        float acc = p.o_b[tid];
        const float* row = p.o_w + tid * 32;
        #pragma unroll
        for (int c = 0; c < 32; ++c) acc = fmaf(row[c], sOutV[c], acc);
        float zv2 = sZ[tid] + p.coupling[0] * acc;
        sZn[tid] = mish_f(zv2);
      }
      __syncthreads();
      if (tid < 32) {
        int par = tid & 1;
        float m = 0.f;
        #pragma unroll
        for (int e = 0; e < 16; ++e) m += sZn[2 * e + par];
        m *= (1.f / 16.f);
        float v = 0.f;
        #pragma unroll
        for (int e = 0; e < 16; ++e) { float dd = sZn[2 * e + par] - m; v = fmaf(dd, dd, v); }
        v *= (1.f / 16.f);
        sZ[tid] = (sZn[tid] - m) * rsqrtf(v + 1e-5f) * p.norm_scale[0];
      }
      __syncthreads();

      if (iter == MSTEPS - 1) {
        if (tid < 32) p.out[tid] = sZ[tid];
      } else {
        compute_qar(p, tid, sZ, sQ, sA, sRel);   // ends with __syncthreads
        if (tid < 128) p.bcast[tid] = sA[tid];
        else if (tid < 384) p.bcast[tid] = sRel[tid - 128];
        __threadfence();
        __syncthreads();
        if (tid == 0)
          __hip_atomic_store(&p.syn[iter], 1, __ATOMIC_RELEASE, __HIP_MEMORY_SCOPE_AGENT);
      }
    } else if (iter < MSTEPS - 1) {
      // ---- wait for the new tables ----
      if (tid == 0) {
        while (__hip_atomic_load(&p.syn[iter], __ATOMIC_ACQUIRE, __HIP_MEMORY_SCOPE_AGENT) == 0)
          __builtin_amdgcn_s_sleep(2);
      }
      __syncthreads();
      if (tid < 128) sA[tid] = p.bcast[tid];
      else if (tid < 384) sRel[tid - 128] = p.bcast[tid];
      __syncthreads();
    }
  }
}

extern "C" void kernel_launch(void* const* d_in, const int* in_sizes, int n_in,
                              void* d_out, int out_size, void* d_ws, size_t ws_size,
                              hipStream_t stream) {
  PParams p;
  p.candidate  = (const float*)d_in[0];
  p.z_past     = (const float*)d_in[1];
  p.q_w = (const float*)d_in[2];  p.q_b = (const float*)d_in[3];
  p.k_w = (const float*)d_in[4];  p.k_b = (const float*)d_in[5];
  p.v_w = (const float*)d_in[6];  p.v_b = (const float*)d_in[7];
  p.o_w = (const float*)d_in[8];  p.o_b = (const float*)d_in[9];
  p.rel_bias   = (const float*)d_in[10];
  p.coupling   = (const float*)d_in[11];
  p.norm_scale = (const float*)d_in[12];
  p.out  = (float*)d_out;
  p.L    = in_sizes[1] / 32;

  const size_t zh_bytes    = (size_t)p.L * 32 * sizeof(ushort);
  const size_t part_bytes  = 2u * 132u * NBMAX * sizeof(float);
  const size_t bcast_bytes = 384 * sizeof(float);
  const size_t syn_bytes   = 16 * sizeof(int);
  const bool use_f16 = (ws_size >= zh_bytes + part_bytes + bcast_bytes + syn_bytes);

  const void* kfun = use_f16 ? (const void*)photonic_kernel<true>
                             : (const void*)photonic_kernel<false>;

  int occ = 0;
  if (hipOccupancyMaxActiveBlocksPerMultiprocessor(
          &occ, kfun, BT, 0) != hipSuccess || occ < 1) occ = 1;
  if (occ > 2) occ = 2;
  int nb = 256 * occ;

  char* ws = (char*)d_ws;
  if (use_f16) {
    p.zh   = (const ushort*)ws;
    p.part = (float*)(ws + zh_bytes);
    p.bcast= (float*)(ws + zh_bytes + part_bytes);
    p.syn  = (int*)  (ws + zh_bytes + part_bytes + bcast_bytes);
  } else {
    p.zh   = nullptr;
    p.part = (float*)ws;
    p.bcast= (float*)(ws + part_bytes);
    p.syn  = (int*)  (ws + part_bytes + bcast_bytes);
  }
  p.NB = nb;
  p.NQ = nb * (BT / 4);

  init_kernel<<<1, 64, 0, stream>>>(p.syn);
  if (use_f16) {
    int n8 = p.L * 4;  // groups of 8 elements
    cvt_kernel<<<(n8 + 255) / 256, 256, 0, stream>>>(p.z_past, (ushort*)p.zh, n8);
  }

  void* args[] = { &p };
  hipLaunchCooperativeKernel(kfun, dim3(nb), dim3(BT), args, 0, stream);
}

// Round 6
// 576.828 us; speedup vs baseline: 2.5891x; 2.5891x over previous
//
#include <hip/hip_runtime.h>
#include <hip/hip_fp16.h>
#include <hip/hip_cooperative_groups.h>

namespace cg = cooperative_groups;

#define NB 256            // blocks (1 per CU; 137 KB LDS forces this anyway)
#define BT 1024           // threads per block (16 waves)
#define QS (BT / 4)       // 256 quads per block
#define MSTEPS 8

struct PParams {
  const float* candidate;
  const float* z_past;
  const float* q_w; const float* q_b;
  const float* k_w; const float* k_b;
  const float* v_w; const float* v_b;
  const float* o_w; const float* o_b;
  const float* rel_bias;
  const float* coupling;
  const float* norm_scale;
  float* out;
  float* part;   // 2 * 132 * NB floats (double-buffered partials)
  int L;
  int chunk;     // ceil(L / NB) positions per block
};

__device__ __forceinline__ float mish_f(float x) {
  float sp = fmaxf(x, 0.0f) + log1pf(expf(-fabsf(x)));
  return x * tanhf(sp);
}

__device__ __forceinline__ uint4 pack8(const float4& a, const float4& c) {
  __half2 h0 = __floats2half2_rn(a.x, a.y);
  __half2 h1 = __floats2half2_rn(a.z, a.w);
  __half2 h2 = __floats2half2_rn(c.x, c.y);
  __half2 h3 = __floats2half2_rn(c.z, c.w);
  uint4 u;
  u.x = *reinterpret_cast<unsigned*>(&h0);
  u.y = *reinterpret_cast<unsigned*>(&h1);
  u.z = *reinterpret_cast<unsigned*>(&h2);
  u.w = *reinterpret_cast<unsigned*>(&h3);
  return u;
}

__device__ __forceinline__ void cvt8(const uint4& r, float zv[8]) {
  const __half2* h = reinterpret_cast<const __half2*>(&r);
  float2 f0 = __half22float2(h[0]);
  float2 f1 = __half22float2(h[1]);
  float2 f2 = __half22float2(h[2]);
  float2 f3 = __half22float2(h[3]);
  zv[0] = f0.x; zv[1] = f0.y; zv[2] = f1.x; zv[3] = f1.y;
  zv[4] = f2.x; zv[5] = f2.y; zv[6] = f3.x; zv[7] = f3.y;
}

template <bool REL>
__device__ __forceinline__ void accum_pos(const float A[4][8], const float zv[8],
                                          float S[4][8], float Zc[4],
                                          const float* sRel, int l) {
  float d[4] = {0.f, 0.f, 0.f, 0.f};
  #pragma unroll
  for (int h = 0; h < 4; ++h)
    #pragma unroll
    for (int k = 0; k < 8; ++k) d[h] = fmaf(A[h][k], zv[k], d[h]);
  #pragma unroll
  for (int h = 0; h < 4; ++h) {
    d[h] += __shfl_xor(d[h], 1);
    d[h] += __shfl_xor(d[h], 2);
  }
  if (REL) {
    if (l < 64) {
      const float4 r = reinterpret_cast<const float4*>(sRel)[l];
      d[0] += r.x; d[1] += r.y; d[2] += r.z; d[3] += r.w;
    }
  }
  #pragma unroll
  for (int h = 0; h < 4; ++h) {
    float w = __expf(d[h]);
    Zc[h] += w;
    #pragma unroll
    for (int k = 0; k < 8; ++k) S[h][k] = fmaf(w, zv[k], S[h][k]);
  }
}

// q projection -> folded score vectors a_h (pre-scaled by inv_sqrt_d=0.5) and
// the l<64 rel-bias delta table. Called by all threads (contains barriers).
__device__ void compute_qar(const PParams& p, int tid,
                            float* sZ, float* sQ, float* sA, float* sRel) {
  if (tid < 32) {
    float acc = p.q_b[tid];
    const float* row = p.q_w + tid * 32;
    #pragma unroll
    for (int c = 0; c < 32; ++c) acc = fmaf(row[c], sZ[c], acc);
    sQ[tid] = acc;
  }
  __syncthreads();
  if (tid < 128) {
    int h = tid >> 5, c = tid & 31;
    float acc = 0.f;
    #pragma unroll
    for (int jj = 0; jj < 8; ++jj)
      acc = fmaf(sQ[8 * h + jj], p.k_w[(8 * h + jj) * 32 + c], acc);
    sA[tid] = 0.5f * acc;               // fold inv_sqrt_d
  }
  if (tid >= 256 && tid < 512) {
    // delta vs the saturated idx=128 entry (constant part cancels in softmax)
    int t = tid - 256;
    int l = t >> 2, h = t & 3;
    float acc = 0.f;
    #pragma unroll
    for (int jj = 0; jj < 8; ++jj) {
      int jidx = 8 * h + jj;
      acc = fmaf(sQ[jidx],
                 p.rel_bias[(l + 64) * 32 + jidx] - p.rel_bias[128 * 32 + jidx],
                 acc);
    }
    sRel[t] = 0.5f * acc;
  }
  __syncthreads();
}

template <bool USE_LDS>
__global__ __launch_bounds__(BT)
void photonic_kernel(PParams p) {
  cg::grid_group grid = cg::this_grid();

  extern __shared__ __align__(16) char dynLds[];   // chunk*64 B fp16 z-stash
  uint4* zl = reinterpret_cast<uint4*>(dynLds);

  __shared__ __align__(16) float sZ[32];
  __shared__ float sQ[32];
  __shared__ float sOutV[32];
  __shared__ float sZn[32];
  __shared__ __align__(16) float sA[128];     // a[h][c]
  __shared__ __align__(16) float sRel[256];   // relT[l][h], l<64
  __shared__ float sRed[BT / 64][4][36];      // per-wave reduced (S[4][8]+Z[4]) per quarter
  __shared__ float sSS[128];
  __shared__ float sSZ[4];

  const int tid  = threadIdx.x;
  const int b    = blockIdx.x;
  const int j    = tid & 3;        // quarter (owns columns [8j, 8j+8))
  const int quad = tid >> 2;
  const int wave = tid >> 6;
  const int lane = tid & 63;
  const int start = b * p.chunk;
  int end = start + p.chunk; if (end > p.L) end = p.L;

  if (tid < 32) sZ[tid] = p.candidate[tid];
  __syncthreads();
  compute_qar(p, tid, sZ, sQ, sA, sRel);

  for (int iter = 0; iter < MSTEPS; ++iter) {
    float A[4][8];
    #pragma unroll
    for (int h = 0; h < 4; ++h)
      #pragma unroll
      for (int k = 0; k < 8; ++k)
        A[h][k] = sA[h * 32 + j * 8 + k];

    float S[4][8];
    #pragma unroll
    for (int h = 0; h < 4; ++h)
      #pragma unroll
      for (int k = 0; k < 8; ++k) S[h][k] = 0.f;
    float Zc[4] = {0.f, 0.f, 0.f, 0.f};

    if (!USE_LDS || iter == 0) {
      // global fp32 read; round-trip through fp16 so all iters see identical values
      const float4* zp = reinterpret_cast<const float4*>(p.z_past) + j * 2;
      int l = start + quad;
      if (l < end) {
        float4 a = zp[(size_t)l * 8], c = zp[(size_t)l * 8 + 1];
        uint4 u = pack8(a, c);
        if (USE_LDS) zl[(size_t)(l - start) * 4 + j] = u;
        float zv[8]; cvt8(u, zv);
        accum_pos<true>(A, zv, S, Zc, sRel, l);
      }
      for (l += QS; l < end; l += QS) {
        float4 a = zp[(size_t)l * 8], c = zp[(size_t)l * 8 + 1];
        uint4 u = pack8(a, c);
        if (USE_LDS) zl[(size_t)(l - start) * 4 + j] = u;
        float zv[8]; cvt8(u, zv);
        accum_pos<false>(A, zv, S, Zc, sRel, l);
      }
    } else {
      // LDS-resident sweep: each lane re-reads exactly what it wrote (no barrier needed)
      const uint4* zq = zl + j;
      int l = start + quad, idx = quad;
      if (l < end) {
        uint4 u = zq[(size_t)idx * 4];
        float zv[8]; cvt8(u, zv);
        accum_pos<true>(A, zv, S, Zc, sRel, l);
      }
      for (l += QS, idx += QS; l < end; l += QS, idx += QS) {
        uint4 u = zq[(size_t)idx * 4];
        float zv[8]; cvt8(u, zv);
        accum_pos<false>(A, zv, S, Zc, sRel, l);
      }
    }

    // reduce across the 16 quads of each wave (lane%4 == quarter preserved)
    #pragma unroll
    for (int m = 4; m <= 32; m <<= 1) {
      #pragma unroll
      for (int h = 0; h < 4; ++h) {
        #pragma unroll
        for (int k = 0; k < 8; ++k) S[h][k] += __shfl_xor(S[h][k], m);
        Zc[h] += __shfl_xor(Zc[h], m);
      }
    }
    if ((lane >> 2) == 0) {  // lanes 0..3: lane == quarter j
      #pragma unroll
      for (int h = 0; h < 4; ++h) {
        #pragma unroll
        for (int k = 0; k < 8; ++k) sRed[wave][lane][h * 8 + k] = S[h][k];
        sRed[wave][lane][32 + h] = Zc[h];
      }
    }
    __syncthreads();

    // per-block partials -> global, component-major [comp][NB] for coalesced reduce
    float* part = p.part + (iter & 1) * (132 * NB);
    if (tid < 132) {
      float acc = 0.f;
      if (tid < 128) {
        int h = tid >> 5, c = tid & 31;
        int jj = c >> 3, k = c & 7;
        #pragma unroll
        for (int w2 = 0; w2 < BT / 64; ++w2) acc += sRed[w2][jj][h * 8 + k];
        part[(h * 33 + c) * NB + b] = acc;
      } else {
        int h = tid - 128;
        #pragma unroll
        for (int w2 = 0; w2 < BT / 64; ++w2) acc += sRed[w2][0][32 + h];
        part[(h * 33 + 32) * NB + b] = acc;
      }
    }
    grid.sync();

    // every block redundantly reduces all partials (135 KB, L3-resident).
    // 4 threads per component, 132 components -> 528 threads (<= BT=1024).
    if (tid < 528) {
      int comp = tid >> 2, seg = tid & 3;
      const float4* pp = reinterpret_cast<const float4*>(part + comp * NB + seg * (NB / 4));
      float acc = 0.f;
      #pragma unroll
      for (int i = 0; i < NB / 16; ++i) {
        float4 v4 = pp[i];
        acc += (v4.x + v4.y) + (v4.z + v4.w);
      }
      acc += __shfl_xor(acc, 1);
      acc += __shfl_xor(acc, 2);
      if (seg == 0) {
        int h = comp / 33, k = comp % 33;
        if (k < 32) sSS[h * 32 + k] = acc; else sSZ[h] = acc;
      }
    }
    __syncthreads();

    // out_flat[j'] = v_w[j',:] @ (S_h / Z_h) + v_b[j']   (h = j'>>3)
    if (tid < 32) {
      int h = tid >> 3;
      float acc = 0.f;
      const float* row = p.v_w + tid * 32;
      #pragma unroll
      for (int c = 0; c < 32; ++c) acc = fmaf(row[c], sSS[h * 32 + c], acc);
      sOutV[tid] = acc / sSZ[h] + p.v_b[tid];
    }
    __syncthreads();
    // mod = o_w @ out + o_b ; z += coupling*mod ; mish
    if (tid < 32) {
      float acc = p.o_b[tid];
      const float* row = p.o_w + tid * 32;
      #pragma unroll
      for (int c = 0; c < 32; ++c) acc = fmaf(row[c], sOutV[c], acc);
      float zv2 = sZ[tid] + p.coupling[0] * acc;
      sZn[tid] = mish_f(zv2);
    }
    __syncthreads();
    // layer-norm over the 16 real / 16 imag components separately
    if (tid < 32) {
      int par = tid & 1;
      float m = 0.f;
      #pragma unroll
      for (int e = 0; e < 16; ++e) m += sZn[2 * e + par];
      m *= (1.f / 16.f);
      float v = 0.f;
      #pragma unroll
      for (int e = 0; e < 16; ++e) { float dd = sZn[2 * e + par] - m; v = fmaf(dd, dd, v); }
      v *= (1.f / 16.f);
      sZ[tid] = (sZn[tid] - m) * rsqrtf(v + 1e-5f) * p.norm_scale[0];
    }
    __syncthreads();

    if (iter == MSTEPS - 1) {
      if (b == 0 && tid < 32) p.out[tid] = sZ[tid];
    } else {
      compute_qar(p, tid, sZ, sQ, sA, sRel);
    }
  }
}

extern "C" void kernel_launch(void* const* d_in, const int* in_sizes, int n_in,
                              void* d_out, int out_size, void* d_ws, size_t ws_size,
                              hipStream_t stream) {
  PParams p;
  p.candidate  = (const float*)d_in[0];
  p.z_past     = (const float*)d_in[1];
  p.q_w = (const float*)d_in[2];  p.q_b = (const float*)d_in[3];
  p.k_w = (const float*)d_in[4];  p.k_b = (const float*)d_in[5];
  p.v_w = (const float*)d_in[6];  p.v_b = (const float*)d_in[7];
  p.o_w = (const float*)d_in[8];  p.o_b = (const float*)d_in[9];
  p.rel_bias   = (const float*)d_in[10];
  p.coupling   = (const float*)d_in[11];
  p.norm_scale = (const float*)d_in[12];
  p.out  = (float*)d_out;
  p.part = (float*)d_ws;
  p.L    = in_sizes[1] / 32;
  p.chunk = (p.L + NB - 1) / NB;

  const size_t dynBytes = (size_t)p.chunk * 64;   // fp16 chunk stash (~122 KB at L=500k)
  void* args[] = { &p };

  // gfx950 LDS is 160 KiB/CU; raise the dynamic-LDS cap (ignore failure).
  (void)hipFuncSetAttribute((const void*)photonic_kernel<true>,
                            hipFuncAttributeMaxDynamicSharedMemorySize,
                            (int)dynBytes);

  hipError_t err = hipLaunchCooperativeKernel((const void*)photonic_kernel<true>,
                                              dim3(NB), dim3(BT), args, dynBytes, stream);
  if (err != hipSuccess) {
    (void)hipGetLastError();   // clear, fall back to the no-LDS variant
    hipLaunchCooperativeKernel((const void*)photonic_kernel<false>,
                               dim3(NB), dim3(BT), args, 0, stream);
  }
}